// Round 5
// baseline (3409.295 us; speedup 1.0000x reference)
//
#include <hip/hip_runtime.h>

#define O_N 100000
#define R_N 1000000
#define DIM 128
#define SD 384
#define HD 256
#define BR 32

typedef __attribute__((ext_vector_type(8))) short short8;
typedef __attribute__((ext_vector_type(4))) float f32x4;
typedef __attribute__((ext_vector_type(4))) unsigned short bfu16x4;

static __device__ __forceinline__ unsigned short f2bf(float x) {
    union { float f; unsigned int u; } v; v.f = x;
    unsigned int r = v.u + 0x7FFFu + ((v.u >> 16) & 1u);
    return (unsigned short)(r >> 16);
}
static __device__ __forceinline__ float bf2f(unsigned short b) {
    union { unsigned int u; float f; } v; v.u = ((unsigned int)b) << 16;
    return v.f;
}

// packed bf16x2 atomic add (gfx950 native; inline asm avoids header dependence)
static __device__ __forceinline__ void atomic_pk_bf16(unsigned short* p, unsigned int pk) {
    unsigned long long addr = (unsigned long long)p;
    asm volatile("global_atomic_pk_add_bf16 %0, %1, off" : : "v"(addr), "v"(pk) : "memory");
}

// ---- K0: transpose + convert weights to bf16 ----------------------------
__global__ void prep_weights(const float* __restrict__ W1, const float* __restrict__ W2,
                             unsigned short* __restrict__ W1T, unsigned short* __restrict__ W2T) {
    int i = blockIdx.x * 256 + threadIdx.x;
    if (i < SD * HD) {                 // W1T[h][k] = W1[k][h]
        int h = i / SD, k = i - h * SD;
        W1T[i] = f2bf(W1[k * HD + h]);
    } else {
        int j = i - SD * HD;           // W2T[c][k] = W2[k][c]
        int c = j / HD, k = j - c * HD;
        W2T[j] = f2bf(W2[k * SD + c]);
    }
}

// ---- K2: triplet copy (as float) + degree counts ------------------------
__global__ void trip_cnt(const int* __restrict__ trip, float* __restrict__ tripOut,
                         float* __restrict__ lenOut, float* __restrict__ cnt,
                         const int* __restrict__ tlen) {
    int i = blockIdx.x * 256 + threadIdx.x;
    if (i < R_N) {
        int s = trip[3 * i], o = trip[3 * i + 1], t2 = trip[3 * i + 2];
        tripOut[3 * i]     = (float)s;
        tripOut[3 * i + 1] = (float)o;
        tripOut[3 * i + 2] = (float)t2;
        atomicAdd(&cnt[min(max(s, 0), O_N - 1)], 1.0f);
        atomicAdd(&cnt[min(max(o, 0), O_N - 1)], 1.0f);
        if (i == 0) lenOut[0] = (float)tlen[0];
    }
}

// ---- K3: main fused gather -> MLP -> scatter kernel ----------------------
// Round-5: BR 64 -> 32. LDS 24832 B -> 6 blocks/CU (24 waves/CU), doubling
// latency-hiding TLP. Per-CU totals (atomics, MFMA, bytes) unchanged.
__global__ __launch_bounds__(256, 6)
void mlp_kernel(const float* __restrict__ objF, const float* __restrict__ relF,
                const unsigned short* __restrict__ W1T, const unsigned short* __restrict__ W2T,
                const float* __restrict__ b1, const float* __restrict__ b2,
                const int* __restrict__ trip,
                unsigned short* __restrict__ accB, float* __restrict__ relOut) {
    __shared__ __align__(16) unsigned char smem[24832];
    unsigned char* Xs = smem;             // 24576 B : X[32][384] bf16, swizzled
    unsigned char* Hs = smem;             // aliased: H[32][256] bf16, swizzled (16384 B)
    int* idxBuf = (int*)(smem + 24576);   // [0..31]=sub, [32..63]=obj

    const int tid  = threadIdx.x;
    const int lane = tid & 63;
    const int w    = tid >> 6;
    const int r0   = blockIdx.x * BR;
    const int l15  = lane & 15;
    const int l4   = lane >> 4;

    if (tid < 2 * BR) {
        int rr = r0 + (tid & (BR - 1));
        int which = tid >> 5;             // 0 = sub, 1 = obj
        idxBuf[tid] = min(max(trip[3 * rr + which], 0), O_N - 1);
    }
    __syncthreads();

    // ---- fill Xs: 32 rows x 96 float4-units, convert f32 -> bf16 --------
    #pragma unroll
    for (int it = 0; it < 12; ++it) {
        int idx = it * 256 + tid;
        int row = idx / 96;
        int c4  = idx - row * 96;
        const float* src;
        if (c4 < 32)      src = objF + (size_t)idxBuf[row] * DIM + c4 * 4;
        else if (c4 < 64) src = relF + (size_t)(r0 + row) * DIM + (c4 - 32) * 4;
        else              src = objF + (size_t)idxBuf[BR + row] * DIM + (c4 - 64) * 4;
        f32x4 v = *(const f32x4*)src;
        unsigned long long pk =  (unsigned long long)f2bf(v.x)
                              | ((unsigned long long)f2bf(v.y) << 16)
                              | ((unsigned long long)f2bf(v.z) << 32)
                              | ((unsigned long long)f2bf(v.w) << 48);
        int byteoff = row * 768 + ((((c4 >> 1) ^ (row & 15)) << 4) + (c4 & 1) * 8);
        *(unsigned long long*)(Xs + byteoff) = pk;
    }
    __syncthreads();

    // ---- GEMM1 (swapped): D1[h][rel] = W1T(A) * X^T(B), wave owns 64 h --
    const int hW = w * 64;
    f32x4 acc1[4][2];
    #pragma unroll
    for (int a = 0; a < 4; ++a)
        #pragma unroll
        for (int b = 0; b < 2; ++b) acc1[a][b] = (f32x4)0.0f;

    #pragma unroll
    for (int ks = 0; ks < 12; ++ks) {
        int k0 = ks * 32;
        short8 af[4], bfr[2];
        #pragma unroll
        for (int mh = 0; mh < 4; ++mh) {
            int h = hW + mh * 16 + l15;
            af[mh] = *(const short8*)(W1T + h * SD + k0 + 8 * l4);
        }
        #pragma unroll
        for (int nr = 0; nr < 2; ++nr) {
            int rel = nr * 16 + l15;
            int kb  = (k0 >> 3) + l4;
            bfr[nr] = *(const short8*)(Xs + rel * 768 + ((kb ^ (rel & 15)) << 4));
        }
        #pragma unroll
        for (int mh = 0; mh < 4; ++mh)
            #pragma unroll
            for (int nr = 0; nr < 2; ++nr)
                acc1[mh][nr] = __builtin_amdgcn_mfma_f32_16x16x32_bf16(
                    af[mh], bfr[nr], acc1[mh][nr], 0, 0, 0);
    }
    __syncthreads();   // all waves done READING Xs before pack overwrites it

    // ---- bias + relu + pack -> Hs[rel][h] (bf16, swizzled, aliases Xs) --
    #pragma unroll
    for (int mh = 0; mh < 4; ++mh) {
        int hbase = hW + mh * 16 + 4 * l4;
        float bb0 = b1[hbase], bb1 = b1[hbase + 1], bb2 = b1[hbase + 2], bb3 = b1[hbase + 3];
        int hb   = hbase >> 3;
        int half = (hbase >> 2) & 1;
        #pragma unroll
        for (int nr = 0; nr < 2; ++nr) {
            int rel = nr * 16 + l15;
            unsigned long long pk =
                  (unsigned long long)f2bf(fmaxf(acc1[mh][nr][0] + bb0, 0.f))
                | ((unsigned long long)f2bf(fmaxf(acc1[mh][nr][1] + bb1, 0.f)) << 16)
                | ((unsigned long long)f2bf(fmaxf(acc1[mh][nr][2] + bb2, 0.f)) << 32)
                | ((unsigned long long)f2bf(fmaxf(acc1[mh][nr][3] + bb3, 0.f)) << 48);
            *(unsigned long long*)(Hs + rel * 512 + ((hb ^ (rel & 15)) << 4) + half * 8) = pk;
        }
    }
    __syncthreads();

    // ---- GEMM2: D2[rel][c] = H(A) * W2T(B), wave owns 96 out-cols -------
    const int cW = w * 96;
    f32x4 acc2[2][6];
    #pragma unroll
    for (int a = 0; a < 2; ++a)
        #pragma unroll
        for (int b = 0; b < 6; ++b) acc2[a][b] = (f32x4)0.0f;

    #pragma unroll
    for (int ks = 0; ks < 8; ++ks) {
        int k0 = ks * 32;
        short8 ha[2], wb[6];
        #pragma unroll
        for (int ma = 0; ma < 2; ++ma) {
            int rel = ma * 16 + l15;
            int hb  = (k0 >> 3) + l4;
            ha[ma] = *(const short8*)(Hs + rel * 512 + ((hb ^ (rel & 15)) << 4));
        }
        #pragma unroll
        for (int nb = 0; nb < 6; ++nb) {
            int c = cW + nb * 16 + l15;
            wb[nb] = *(const short8*)(W2T + c * HD + k0 + 8 * l4);
        }
        #pragma unroll
        for (int ma = 0; ma < 2; ++ma)
            #pragma unroll
            for (int nb = 0; nb < 6; ++nb)
                acc2[ma][nb] = __builtin_amdgcn_mfma_f32_16x16x32_bf16(
                    ha[ma], wb[nb], acc2[ma][nb], 0, 0, 0);
    }

    // ---- epilogue: bias + region-split store / packed scatter-add -------
    const int evenLane = ((lane & 1) == 0);
    #pragma unroll
    for (int ma = 0; ma < 2; ++ma) {
        int rloc = ma * 16 + 4 * l4;
        int rg   = r0 + rloc;
        int subs[4], objs[4];
        #pragma unroll
        for (int q = 0; q < 4; ++q) {
            subs[q] = idxBuf[rloc + q];
            objs[q] = idxBuf[BR + rloc + q];
        }
        #pragma unroll
        for (int nb = 0; nb < 6; ++nb) {
            int c = cW + nb * 16 + l15;
            float b2v = b2[c];
            #pragma unroll
            for (int q = 0; q < 4; ++q) {
                float v = acc2[ma][nb][q] + b2v;
                if (c >= DIM && c < 2 * DIM) {
                    relOut[(size_t)(rg + q) * DIM + (c - DIM)] = v;
                } else {
                    // pair columns (c even, c+1) across adjacent lanes, one
                    // pk_add_bf16 per pair from the even lane
                    float pv = __shfl_xor(v, 1);
                    if (evenLane) {
                        unsigned int pk = (unsigned int)f2bf(v) | ((unsigned int)f2bf(pv) << 16);
                        int row = (c < DIM) ? subs[q] : objs[q];
                        int cc  = (c < DIM) ? c : (c - 2 * DIM);
                        atomic_pk_bf16(accB + (size_t)row * DIM + cc, pk);
                    }
                }
            }
        }
    }
}

// ---- K4: output_feat = acc(bf16) / max(cnt,1) + object_feats -------------
__global__ void finalize(const unsigned short* __restrict__ accB, const float* __restrict__ cnt,
                         const float* __restrict__ objF, float* __restrict__ outF) {
    int i = blockIdx.x * 256 + threadIdx.x;      // float4 index
    if (i < O_N * DIM / 4) {
        int row = i >> 5;                        // DIM/4 = 32 float4 per row
        float c = fmaxf(cnt[row], 1.0f);
        bfu16x4 a = *(const bfu16x4*)(accB + (size_t)i * 4);
        f32x4 o = ((const f32x4*)objF)[i];
        f32x4 r;
        r.x = bf2f(a.x) / c + o.x;
        r.y = bf2f(a.y) / c + o.y;
        r.z = bf2f(a.z) / c + o.z;
        r.w = bf2f(a.w) / c + o.w;
        ((f32x4*)outF)[i] = r;
    }
}

extern "C" void kernel_launch(void* const* d_in, const int* in_sizes, int n_in,
                              void* d_out, int out_size, void* d_ws, size_t ws_size,
                              hipStream_t stream) {
    const float* objF = (const float*)d_in[0];
    const float* relF = (const float*)d_in[1];
    const float* W1   = (const float*)d_in[2];
    const float* b1   = (const float*)d_in[3];
    const float* W2   = (const float*)d_in[4];
    const float* b2   = (const float*)d_in[5];
    const int*   trip = (const int*)d_in[6];
    const int*   tlen = (const int*)d_in[7];

    float* outF    = (float*)d_out;
    float* relOut  = outF + (size_t)O_N * DIM;          // 12.8M
    float* tripOut = relOut + (size_t)R_N * DIM;        // +128M
    float* lenOut  = tripOut + (size_t)R_N * 3;         // +3M

    unsigned short* W1T = (unsigned short*)d_ws;
    unsigned short* W2T = W1T + SD * HD;
    unsigned short* accB = W2T + SD * HD;               // bf16 accumulator
    float* cnt = (float*)(accB + (size_t)O_N * DIM);

    (void)hipMemsetAsync(accB, 0, (size_t)O_N * DIM * 2 + O_N * 4, stream);
    prep_weights<<<(2 * SD * HD) / 256, 256, 0, stream>>>(W1, W2, W1T, W2T);
    trip_cnt<<<(R_N + 255) / 256, 256, 0, stream>>>(trip, tripOut, lenOut, cnt, tlen);
    mlp_kernel<<<R_N / BR, 256, 0, stream>>>(objF, relF, W1T, W2T, b1, b2, trip, accB, relOut);
    finalize<<<(O_N * DIM / 4 + 255) / 256, 256, 0, stream>>>(accB, cnt, objF, outF);
}

// Round 6
// 1957.312 us; speedup vs baseline: 1.7418x; 1.7418x over previous
//
#include <hip/hip_runtime.h>

#define O_N 100000
#define R_N 1000000
#define DIM 128
#define SD 384
#define HD 256
#define BR 32

typedef __attribute__((ext_vector_type(8))) short short8;
typedef __attribute__((ext_vector_type(4))) float f32x4;

static __device__ __forceinline__ unsigned short f2bf(float x) {
    union { float f; unsigned int u; } v; v.f = x;
    unsigned int r = v.u + 0x7FFFu + ((v.u >> 16) & 1u);
    return (unsigned short)(r >> 16);
}

// ---- K0: transpose + convert weights to bf16 ----------------------------
__global__ void prep_weights(const float* __restrict__ W1, const float* __restrict__ W2,
                             unsigned short* __restrict__ W1T, unsigned short* __restrict__ W2T) {
    int i = blockIdx.x * 256 + threadIdx.x;
    if (i < SD * HD) {                 // W1T[h][k] = W1[k][h]
        int h = i / SD, k = i - h * SD;
        W1T[i] = f2bf(W1[k * HD + h]);
    } else {
        int j = i - SD * HD;           // W2T[c][k] = W2[k][c]
        int c = j / HD, k = j - c * HD;
        W2T[j] = f2bf(W2[k * SD + c]);
    }
}

// ---- K2: triplet copy (as float) + degree counts ------------------------
__global__ void trip_cnt(const int* __restrict__ trip, float* __restrict__ tripOut,
                         float* __restrict__ lenOut, float* __restrict__ cnt,
                         const int* __restrict__ tlen) {
    int i = blockIdx.x * 256 + threadIdx.x;
    if (i < R_N) {
        int s = trip[3 * i], o = trip[3 * i + 1], t2 = trip[3 * i + 2];
        tripOut[3 * i]     = (float)s;
        tripOut[3 * i + 1] = (float)o;
        tripOut[3 * i + 2] = (float)t2;
        atomicAdd(&cnt[min(max(s, 0), O_N - 1)], 1.0f);
        atomicAdd(&cnt[min(max(o, 0), O_N - 1)], 1.0f);
        if (i == 0) lenOut[0] = (float)tlen[0];
    }
}

// ---- K3: main fused gather -> MLP -> scatter kernel ----------------------
// Round-6: BR=32 with __launch_bounds__(256,4) (VGPR cap 128 -> no spill;
// round 5's (256,6) cap forced VGPR=40 + scratch spills = 6 GB extra HBM
// traffic). Scatter reverted to plain f32 atomicAdd (round 4 showed packed
// atomics neutral on RMW throughput; shuffle packing cost ~75us VALU).
__global__ __launch_bounds__(256, 4)
void mlp_kernel(const float* __restrict__ objF, const float* __restrict__ relF,
                const unsigned short* __restrict__ W1T, const unsigned short* __restrict__ W2T,
                const float* __restrict__ b1, const float* __restrict__ b2,
                const int* __restrict__ trip,
                float* __restrict__ accB, float* __restrict__ relOut) {
    __shared__ __align__(16) unsigned char smem[24832];
    unsigned char* Xs = smem;             // 24576 B : X[32][384] bf16, swizzled
    unsigned char* Hs = smem;             // aliased: H[32][256] bf16, swizzled (16384 B)
    int* idxBuf = (int*)(smem + 24576);   // [0..31]=sub, [32..63]=obj

    const int tid  = threadIdx.x;
    const int lane = tid & 63;
    const int w    = tid >> 6;
    const int r0   = blockIdx.x * BR;
    const int l15  = lane & 15;
    const int l4   = lane >> 4;

    if (tid < 2 * BR) {
        int rr = r0 + (tid & (BR - 1));
        int which = tid >> 5;             // 0 = sub, 1 = obj
        idxBuf[tid] = min(max(trip[3 * rr + which], 0), O_N - 1);
    }
    __syncthreads();

    // ---- fill Xs: 32 rows x 96 float4-units, convert f32 -> bf16 --------
    #pragma unroll
    for (int it = 0; it < 12; ++it) {
        int idx = it * 256 + tid;
        int row = idx / 96;
        int c4  = idx - row * 96;
        const float* src;
        if (c4 < 32)      src = objF + (size_t)idxBuf[row] * DIM + c4 * 4;
        else if (c4 < 64) src = relF + (size_t)(r0 + row) * DIM + (c4 - 32) * 4;
        else              src = objF + (size_t)idxBuf[BR + row] * DIM + (c4 - 64) * 4;
        f32x4 v = *(const f32x4*)src;
        unsigned long long pk =  (unsigned long long)f2bf(v.x)
                              | ((unsigned long long)f2bf(v.y) << 16)
                              | ((unsigned long long)f2bf(v.z) << 32)
                              | ((unsigned long long)f2bf(v.w) << 48);
        int byteoff = row * 768 + ((((c4 >> 1) ^ (row & 15)) << 4) + (c4 & 1) * 8);
        *(unsigned long long*)(Xs + byteoff) = pk;
    }
    __syncthreads();

    // ---- GEMM1 (swapped): D1[h][rel] = W1T(A) * X^T(B), wave owns 64 h --
    const int hW = w * 64;
    f32x4 acc1[4][2];
    #pragma unroll
    for (int a = 0; a < 4; ++a)
        #pragma unroll
        for (int b = 0; b < 2; ++b) acc1[a][b] = (f32x4)0.0f;

    #pragma unroll
    for (int ks = 0; ks < 12; ++ks) {
        int k0 = ks * 32;
        short8 af[4], bfr[2];
        #pragma unroll
        for (int mh = 0; mh < 4; ++mh) {
            int h = hW + mh * 16 + l15;
            af[mh] = *(const short8*)(W1T + h * SD + k0 + 8 * l4);
        }
        #pragma unroll
        for (int nr = 0; nr < 2; ++nr) {
            int rel = nr * 16 + l15;
            int kb  = (k0 >> 3) + l4;
            bfr[nr] = *(const short8*)(Xs + rel * 768 + ((kb ^ (rel & 15)) << 4));
        }
        #pragma unroll
        for (int mh = 0; mh < 4; ++mh)
            #pragma unroll
            for (int nr = 0; nr < 2; ++nr)
                acc1[mh][nr] = __builtin_amdgcn_mfma_f32_16x16x32_bf16(
                    af[mh], bfr[nr], acc1[mh][nr], 0, 0, 0);
    }
    __syncthreads();   // all waves done READING Xs before pack overwrites it

    // ---- bias + relu + pack -> Hs[rel][h] (bf16, swizzled, aliases Xs) --
    #pragma unroll
    for (int mh = 0; mh < 4; ++mh) {
        int hbase = hW + mh * 16 + 4 * l4;
        float bb0 = b1[hbase], bb1 = b1[hbase + 1], bb2 = b1[hbase + 2], bb3 = b1[hbase + 3];
        int hb   = hbase >> 3;
        int half = (hbase >> 2) & 1;
        #pragma unroll
        for (int nr = 0; nr < 2; ++nr) {
            int rel = nr * 16 + l15;
            unsigned long long pk =
                  (unsigned long long)f2bf(fmaxf(acc1[mh][nr][0] + bb0, 0.f))
                | ((unsigned long long)f2bf(fmaxf(acc1[mh][nr][1] + bb1, 0.f)) << 16)
                | ((unsigned long long)f2bf(fmaxf(acc1[mh][nr][2] + bb2, 0.f)) << 32)
                | ((unsigned long long)f2bf(fmaxf(acc1[mh][nr][3] + bb3, 0.f)) << 48);
            *(unsigned long long*)(Hs + rel * 512 + ((hb ^ (rel & 15)) << 4) + half * 8) = pk;
        }
    }
    __syncthreads();

    // ---- GEMM2: D2[rel][c] = H(A) * W2T(B), wave owns 96 out-cols -------
    const int cW = w * 96;
    f32x4 acc2[2][6];
    #pragma unroll
    for (int a = 0; a < 2; ++a)
        #pragma unroll
        for (int b = 0; b < 6; ++b) acc2[a][b] = (f32x4)0.0f;

    #pragma unroll
    for (int ks = 0; ks < 8; ++ks) {
        int k0 = ks * 32;
        short8 ha[2], wb[6];
        #pragma unroll
        for (int ma = 0; ma < 2; ++ma) {
            int rel = ma * 16 + l15;
            int hb  = (k0 >> 3) + l4;
            ha[ma] = *(const short8*)(Hs + rel * 512 + ((hb ^ (rel & 15)) << 4));
        }
        #pragma unroll
        for (int nb = 0; nb < 6; ++nb) {
            int c = cW + nb * 16 + l15;
            wb[nb] = *(const short8*)(W2T + c * HD + k0 + 8 * l4);
        }
        #pragma unroll
        for (int ma = 0; ma < 2; ++ma)
            #pragma unroll
            for (int nb = 0; nb < 6; ++nb)
                acc2[ma][nb] = __builtin_amdgcn_mfma_f32_16x16x32_bf16(
                    ha[ma], wb[nb], acc2[ma][nb], 0, 0, 0);
    }

    // ---- epilogue: bias + region-split store / f32 scatter-add ----------
    #pragma unroll
    for (int ma = 0; ma < 2; ++ma) {
        int rloc = ma * 16 + 4 * l4;
        int rg   = r0 + rloc;
        int subs[4], objs[4];
        #pragma unroll
        for (int q = 0; q < 4; ++q) {
            subs[q] = idxBuf[rloc + q];
            objs[q] = idxBuf[BR + rloc + q];
        }
        #pragma unroll
        for (int nb = 0; nb < 6; ++nb) {
            int c = cW + nb * 16 + l15;
            float b2v = b2[c];
            #pragma unroll
            for (int q = 0; q < 4; ++q) {
                float v = acc2[ma][nb][q] + b2v;
                if (c < DIM) {
                    atomicAdd(accB + (size_t)subs[q] * DIM + c, v);
                } else if (c < 2 * DIM) {
                    relOut[(size_t)(rg + q) * DIM + (c - DIM)] = v;
                } else {
                    atomicAdd(accB + (size_t)objs[q] * DIM + (c - 2 * DIM), v);
                }
            }
        }
    }
}

// ---- K4: output_feat = acc / max(cnt,1) + object_feats -------------------
__global__ void finalize(const float* __restrict__ accB, const float* __restrict__ cnt,
                         const float* __restrict__ objF, float* __restrict__ outF) {
    int i = blockIdx.x * 256 + threadIdx.x;      // float4 index
    if (i < O_N * DIM / 4) {
        int row = i >> 5;                        // DIM/4 = 32 float4 per row
        float c = fmaxf(cnt[row], 1.0f);
        f32x4 a = ((const f32x4*)accB)[i];
        f32x4 o = ((const f32x4*)objF)[i];
        f32x4 r;
        r.x = a.x / c + o.x;
        r.y = a.y / c + o.y;
        r.z = a.z / c + o.z;
        r.w = a.w / c + o.w;
        ((f32x4*)outF)[i] = r;
    }
}

extern "C" void kernel_launch(void* const* d_in, const int* in_sizes, int n_in,
                              void* d_out, int out_size, void* d_ws, size_t ws_size,
                              hipStream_t stream) {
    const float* objF = (const float*)d_in[0];
    const float* relF = (const float*)d_in[1];
    const float* W1   = (const float*)d_in[2];
    const float* b1   = (const float*)d_in[3];
    const float* W2   = (const float*)d_in[4];
    const float* b2   = (const float*)d_in[5];
    const int*   trip = (const int*)d_in[6];
    const int*   tlen = (const int*)d_in[7];

    float* outF    = (float*)d_out;
    float* relOut  = outF + (size_t)O_N * DIM;          // 12.8M
    float* tripOut = relOut + (size_t)R_N * DIM;        // +128M
    float* lenOut  = tripOut + (size_t)R_N * 3;         // +3M

    unsigned short* W1T = (unsigned short*)d_ws;
    unsigned short* W2T = W1T + SD * HD;
    float* accB = (float*)(W2T + SD * HD);
    float* cnt  = accB + (size_t)O_N * DIM;

    (void)hipMemsetAsync(accB, 0, ((size_t)O_N * DIM + O_N) * sizeof(float), stream);
    prep_weights<<<(2 * SD * HD) / 256, 256, 0, stream>>>(W1, W2, W1T, W2T);
    trip_cnt<<<(R_N + 255) / 256, 256, 0, stream>>>(trip, tripOut, lenOut, cnt, tlen);
    mlp_kernel<<<R_N / BR, 256, 0, stream>>>(objF, relF, W1T, W2T, b1, b2, trip, accB, relOut);
    finalize<<<(O_N * DIM / 4 + 255) / 256, 256, 0, stream>>>(accB, cnt, objF, outF);
}

// Round 7
// 1519.061 us; speedup vs baseline: 2.2443x; 1.2885x over previous
//
#include <hip/hip_runtime.h>

#define O_N 100000
#define R_N 1000000
#define DIM 128
#define SD 384
#define HD 256
#define BR 64
#define OBJ8 (O_N * DIM / 8)   // 1.6M 8-elt groups
#define REL8 (R_N * DIM / 8)   // 16M 8-elt groups

typedef __attribute__((ext_vector_type(8))) short short8;
typedef __attribute__((ext_vector_type(4))) float f32x4;

static __device__ __forceinline__ unsigned short f2bf(float x) {
    union { float f; unsigned int u; } v; v.f = x;
    unsigned int r = v.u + 0x7FFFu + ((v.u >> 16) & 1u);
    return (unsigned short)(r >> 16);
}
static __device__ __forceinline__ unsigned long long pack4(f32x4 v) {
    return  (unsigned long long)f2bf(v.x)
         | ((unsigned long long)f2bf(v.y) << 16)
         | ((unsigned long long)f2bf(v.z) << 32)
         | ((unsigned long long)f2bf(v.w) << 48);
}

// ---- K0: transpose + convert weights to bf16 ----------------------------
__global__ void prep_weights(const float* __restrict__ W1, const float* __restrict__ W2,
                             unsigned short* __restrict__ W1T, unsigned short* __restrict__ W2T) {
    int i = blockIdx.x * 256 + threadIdx.x;
    if (i < SD * HD) {                 // W1T[h][k] = W1[k][h]
        int h = i / SD, k = i - h * SD;
        W1T[i] = f2bf(W1[k * HD + h]);
    } else {
        int j = i - SD * HD;           // W2T[c][k] = W2[k][c]
        int c = j / HD, k = j - c * HD;
        W2T[j] = f2bf(W2[k * SD + c]);
    }
}

// ---- K1: pre-convert object_feats + relation_feats to bf16 ---------------
__global__ void conv_bf16(const float* __restrict__ objF, const float* __restrict__ relF,
                          unsigned short* __restrict__ objBF, unsigned short* __restrict__ relBF) {
    long long i = (long long)blockIdx.x * 256 + threadIdx.x;   // one 8-elt group
    if (i >= (long long)OBJ8 + REL8) return;
    const float* s; unsigned short* d;
    if (i < OBJ8) { s = objF + i * 8;           d = objBF + i * 8; }
    else          { long long j = i - OBJ8; s = relF + j * 8; d = relBF + j * 8; }
    f32x4 v0 = ((const f32x4*)s)[0];
    f32x4 v1 = ((const f32x4*)s)[1];
    unsigned long long* dd = (unsigned long long*)d;
    dd[0] = pack4(v0);
    dd[1] = pack4(v1);
}

// ---- K2: triplet copy (as float) + degree counts ------------------------
__global__ void trip_cnt(const int* __restrict__ trip, float* __restrict__ tripOut,
                         float* __restrict__ lenOut, float* __restrict__ cnt,
                         const int* __restrict__ tlen) {
    int i = blockIdx.x * 256 + threadIdx.x;
    if (i < R_N) {
        int s = trip[3 * i], o = trip[3 * i + 1], t2 = trip[3 * i + 2];
        tripOut[3 * i]     = (float)s;
        tripOut[3 * i + 1] = (float)o;
        tripOut[3 * i + 2] = (float)t2;
        atomicAdd(&cnt[min(max(s, 0), O_N - 1)], 1.0f);
        atomicAdd(&cnt[min(max(o, 0), O_N - 1)], 1.0f);
        if (i == 0) lenOut[0] = (float)tlen[0];
    }
}

// ---- K3: main fused gather -> MLP -> scatter kernel ----------------------
// Round-7: fill via global_load_lds (16B/lane, per-lane gather source with
// inverse XOR-swizzle, linear LDS dest). Zero data VGPRs in fill -> all 12
// loads/wave in flight; one vmcnt(0) at the barrier. Inputs pre-converted
// to bf16 by conv_bf16. Config reverted to round-2 best: BR=64, 3 blk/CU,
// plain f32 atomics.
__global__ __launch_bounds__(256, 3)
void mlp_kernel(const unsigned short* __restrict__ objBF, const unsigned short* __restrict__ relBF,
                const unsigned short* __restrict__ W1T, const unsigned short* __restrict__ W2T,
                const float* __restrict__ b1, const float* __restrict__ b2,
                const int* __restrict__ trip,
                float* __restrict__ accB, float* __restrict__ relOut) {
    __shared__ __align__(16) unsigned char smem[49664];
    unsigned char* Xs = smem;             // 49152 B : X[64][384] bf16, swizzled
    unsigned char* Hs = smem;             // aliased: H[64][256] bf16, swizzled
    int* idxBuf = (int*)(smem + 49152);   // [0..63]=sub, [64..127]=obj

    const int tid  = threadIdx.x;
    const int lane = tid & 63;
    const int w    = tid >> 6;
    const int r0   = blockIdx.x * BR;
    const int l15  = lane & 15;
    const int l4   = lane >> 4;

    if (tid < 2 * BR) {
        int rr = r0 + (tid & (BR - 1));
        int which = tid >> 6;             // 0 = sub, 1 = obj
        idxBuf[tid] = min(max(trip[3 * rr + which], 0), O_N - 1);
    }
    __syncthreads();

    // ---- fill Xs: 48 x 1KB segments via global_load_lds ------------------
    // LDS layout: row*768 + p*16, p in [0,48). Stored unit p holds source
    // unit u = p ^ (row&15)  (involution; GEMM1 reads with the same XOR).
    // Source unit u: [0,16)=sub row, [16,32)=relation row, [32,48)=obj row.
    #pragma unroll
    for (int j = 0; j < 12; ++j) {
        int seg = w * 12 + j;             // wave-uniform 1KB segment
        int a   = seg * 64 + lane;        // absolute 16B-unit index [0,3072)
        int row = a / 48;
        int p   = a - row * 48;
        int u   = p ^ (row & 15);
        const unsigned short* src;
        if (u < 16)      src = objBF + (size_t)idxBuf[row] * DIM + u * 8;
        else if (u < 32) src = relBF + (size_t)(r0 + row) * DIM + (u - 16) * 8;
        else             src = objBF + (size_t)idxBuf[BR + row] * DIM + (u - 32) * 8;
        __builtin_amdgcn_global_load_lds(
            (const __attribute__((address_space(1))) void*)src,
            (__attribute__((address_space(3))) void*)(Xs + seg * 1024),
            16, 0, 0);
    }
    __syncthreads();   // compiler emits s_waitcnt vmcnt(0) before barrier

    // ---- GEMM1 (swapped): D1[h][rel] = W1T(A) * X^T(B), wave owns 64 h --
    const int hW = w * 64;
    f32x4 acc1[4][4];
    #pragma unroll
    for (int a = 0; a < 4; ++a)
        #pragma unroll
        for (int b = 0; b < 4; ++b) acc1[a][b] = (f32x4)0.0f;

    #pragma unroll
    for (int ks = 0; ks < 12; ++ks) {
        int k0 = ks * 32;
        short8 af[4], bfr[4];
        #pragma unroll
        for (int mh = 0; mh < 4; ++mh) {
            int h = hW + mh * 16 + l15;
            af[mh] = *(const short8*)(W1T + h * SD + k0 + 8 * l4);
        }
        #pragma unroll
        for (int nr = 0; nr < 4; ++nr) {
            int rel = nr * 16 + l15;
            int kb  = (k0 >> 3) + l4;
            bfr[nr] = *(const short8*)(Xs + rel * 768 + ((kb ^ (rel & 15)) << 4));
        }
        #pragma unroll
        for (int mh = 0; mh < 4; ++mh)
            #pragma unroll
            for (int nr = 0; nr < 4; ++nr)
                acc1[mh][nr] = __builtin_amdgcn_mfma_f32_16x16x32_bf16(
                    af[mh], bfr[nr], acc1[mh][nr], 0, 0, 0);
    }
    __syncthreads();   // all waves done READING Xs before pack overwrites it

    // ---- bias + relu + pack -> Hs[rel][h] (bf16, swizzled, aliases Xs) --
    #pragma unroll
    for (int mh = 0; mh < 4; ++mh) {
        int hbase = hW + mh * 16 + 4 * l4;
        float bb0 = b1[hbase], bb1 = b1[hbase + 1], bb2 = b1[hbase + 2], bb3 = b1[hbase + 3];
        int hb   = hbase >> 3;
        int half = (hbase >> 2) & 1;
        #pragma unroll
        for (int nr = 0; nr < 4; ++nr) {
            int rel = nr * 16 + l15;
            unsigned long long pk =
                  (unsigned long long)f2bf(fmaxf(acc1[mh][nr][0] + bb0, 0.f))
                | ((unsigned long long)f2bf(fmaxf(acc1[mh][nr][1] + bb1, 0.f)) << 16)
                | ((unsigned long long)f2bf(fmaxf(acc1[mh][nr][2] + bb2, 0.f)) << 32)
                | ((unsigned long long)f2bf(fmaxf(acc1[mh][nr][3] + bb3, 0.f)) << 48);
            *(unsigned long long*)(Hs + rel * 512 + ((hb ^ (rel & 15)) << 4) + half * 8) = pk;
        }
    }
    __syncthreads();

    // ---- GEMM2: D2[rel][c] = H(A) * W2T(B), wave owns 96 out-cols -------
    const int cW = w * 96;
    f32x4 acc2[4][6];
    #pragma unroll
    for (int a = 0; a < 4; ++a)
        #pragma unroll
        for (int b = 0; b < 6; ++b) acc2[a][b] = (f32x4)0.0f;

    #pragma unroll
    for (int ks = 0; ks < 8; ++ks) {
        int k0 = ks * 32;
        short8 ha[4], wb[6];
        #pragma unroll
        for (int ma = 0; ma < 4; ++ma) {
            int rel = ma * 16 + l15;
            int hb  = (k0 >> 3) + l4;
            ha[ma] = *(const short8*)(Hs + rel * 512 + ((hb ^ (rel & 15)) << 4));
        }
        #pragma unroll
        for (int nb = 0; nb < 6; ++nb) {
            int c = cW + nb * 16 + l15;
            wb[nb] = *(const short8*)(W2T + c * HD + k0 + 8 * l4);
        }
        #pragma unroll
        for (int ma = 0; ma < 4; ++ma)
            #pragma unroll
            for (int nb = 0; nb < 6; ++nb)
                acc2[ma][nb] = __builtin_amdgcn_mfma_f32_16x16x32_bf16(
                    ha[ma], wb[nb], acc2[ma][nb], 0, 0, 0);
    }

    // ---- epilogue: bias + region-split store / f32 scatter-add ----------
    #pragma unroll
    for (int ma = 0; ma < 4; ++ma) {
        int rloc = ma * 16 + 4 * l4;
        int rg   = r0 + rloc;
        int subs[4], objs[4];
        #pragma unroll
        for (int q = 0; q < 4; ++q) {
            subs[q] = idxBuf[rloc + q];
            objs[q] = idxBuf[BR + rloc + q];
        }
        #pragma unroll
        for (int nb = 0; nb < 6; ++nb) {
            int c = cW + nb * 16 + l15;
            float b2v = b2[c];
            #pragma unroll
            for (int q = 0; q < 4; ++q) {
                float v = acc2[ma][nb][q] + b2v;
                if (c < DIM) {
                    atomicAdd(accB + (size_t)subs[q] * DIM + c, v);
                } else if (c < 2 * DIM) {
                    relOut[(size_t)(rg + q) * DIM + (c - DIM)] = v;
                } else {
                    atomicAdd(accB + (size_t)objs[q] * DIM + (c - 2 * DIM), v);
                }
            }
        }
    }
}

// ---- K4: output_feat = acc / max(cnt,1) + object_feats -------------------
__global__ void finalize(const float* __restrict__ accB, const float* __restrict__ cnt,
                         const float* __restrict__ objF, float* __restrict__ outF) {
    int i = blockIdx.x * 256 + threadIdx.x;      // float4 index
    if (i < O_N * DIM / 4) {
        int row = i >> 5;                        // DIM/4 = 32 float4 per row
        float c = fmaxf(cnt[row], 1.0f);
        f32x4 a = ((const f32x4*)accB)[i];
        f32x4 o = ((const f32x4*)objF)[i];
        f32x4 r;
        r.x = a.x / c + o.x;
        r.y = a.y / c + o.y;
        r.z = a.z / c + o.z;
        r.w = a.w / c + o.w;
        ((f32x4*)outF)[i] = r;
    }
}

extern "C" void kernel_launch(void* const* d_in, const int* in_sizes, int n_in,
                              void* d_out, int out_size, void* d_ws, size_t ws_size,
                              hipStream_t stream) {
    const float* objF = (const float*)d_in[0];
    const float* relF = (const float*)d_in[1];
    const float* W1   = (const float*)d_in[2];
    const float* b1   = (const float*)d_in[3];
    const float* W2   = (const float*)d_in[4];
    const float* b2   = (const float*)d_in[5];
    const int*   trip = (const int*)d_in[6];
    const int*   tlen = (const int*)d_in[7];

    float* outF    = (float*)d_out;
    float* relOut  = outF + (size_t)O_N * DIM;          // 12.8M
    float* tripOut = relOut + (size_t)R_N * DIM;        // +128M
    float* lenOut  = tripOut + (size_t)R_N * 3;         // +3M

    // ws layout (~334 MB): weights | accB | cnt | objBF | relBF
    unsigned short* W1T = (unsigned short*)d_ws;
    unsigned short* W2T = W1T + SD * HD;
    float* accB = (float*)(W2T + SD * HD);
    float* cnt  = accB + (size_t)O_N * DIM;
    unsigned short* objBF = (unsigned short*)(cnt + O_N);
    unsigned short* relBF = objBF + (size_t)O_N * DIM;

    (void)hipMemsetAsync(accB, 0, ((size_t)O_N * DIM + O_N) * sizeof(float), stream);
    prep_weights<<<(2 * SD * HD) / 256, 256, 0, stream>>>(W1, W2, W1T, W2T);
    conv_bf16<<<(OBJ8 + REL8 + 255) / 256, 256, 0, stream>>>(objF, relF, objBF, relBF);
    trip_cnt<<<(R_N + 255) / 256, 256, 0, stream>>>(trip, tripOut, lenOut, cnt, tlen);
    mlp_kernel<<<R_N / BR, 256, 0, stream>>>(objBF, relBF, W1T, W2T, b1, b2, trip, accB, relOut);
    finalize<<<(O_N * DIM / 4 + 255) / 256, 256, 0, stream>>>(accB, cnt, objF, outF);
}